// Round 7
// baseline (1294.603 us; speedup 1.0000x reference)
//
#include <hip/hip_runtime.h>
#include <cmath>

#define B_  16
#define SEQ 2048
#define DIM 1024
#define LDST 40              // legacy stride for g1 LDS tiles

typedef short  short8 __attribute__((ext_vector_type(8)));
typedef short  sh4    __attribute__((ext_vector_type(4)));
typedef float  f32x4  __attribute__((ext_vector_type(4)));

__device__ __forceinline__ unsigned short f2bf(float x) {
  unsigned u = __builtin_bit_cast(unsigned, x);
  return (unsigned short)((u + 0x7fffu + ((u >> 16) & 1u)) >> 16);   // RNE
}
__device__ __forceinline__ float bf2f(unsigned short h) {
  unsigned u = ((unsigned)h) << 16;
  return __builtin_bit_cast(float, u);
}

__device__ __forceinline__ void gl16(const void* g, void* l) {
  __builtin_amdgcn_global_load_lds(
      (const __attribute__((address_space(1))) void*)g,
      (__attribute__((address_space(3))) void*)l, 16, 0, 0);
}

#define VMCNT0   asm volatile("s_waitcnt vmcnt(0)" ::: "memory")
#define LGKMCNT0 asm volatile("s_waitcnt lgkmcnt(0)" ::: "memory")
#define SCHEDB   __builtin_amdgcn_sched_barrier(0)
#define SBAR     __builtin_amdgcn_s_barrier()

// ---------------------------------------------------------------------------
// cvt_ctx: ctx f32 -> chi/clo bf16 planes (into d_out comp region)
// ---------------------------------------------------------------------------
__global__ __launch_bounds__(256) void cvt_ctx(const float* __restrict__ X,
                                               unsigned short* __restrict__ hi,
                                               unsigned short* __restrict__ lo) {
  const size_t N8 = (size_t)B_ * SEQ * DIM / 8;
  for (size_t i = (size_t)blockIdx.x * 256 + threadIdx.x; i < N8;
       i += (size_t)gridDim.x * 256) {
    const size_t base = i * 8;
    float4 a = *(const float4*)&X[base];
    float4 c = *(const float4*)&X[base + 4];
    const float xs[8] = {a.x, a.y, a.z, a.w, c.x, c.y, c.z, c.w};
    short8 h, l;
#pragma unroll
    for (int j = 0; j < 8; ++j) {
      unsigned short hh = f2bf(xs[j]);
      h[j] = (short)hh;
      l[j] = (short)f2bf(xs[j] - bf2f(hh));
    }
    *(short8*)&hi[base] = h;
    *(short8*)&lo[base] = l;
  }
}

// ---------------------------------------------------------------------------
// t_ctx: ctxT[b][d][s] bf16 = ctx[b][s][d]
// ---------------------------------------------------------------------------
__global__ __launch_bounds__(256) void t_ctx(const float* __restrict__ X,
                                             unsigned short* __restrict__ T) {
  __shared__ unsigned short L[64 * 72];
  const int t = threadIdx.x;
  const int d0 = blockIdx.x * 64, s0 = blockIdx.y * 64, b = blockIdx.z;
#pragma unroll
  for (int p = 0; p < 4; ++p) {
    const int sl = (t >> 4) + p * 16, d4 = (t & 15) * 4;
    float4 v = *(const float4*)&X[((size_t)b * SEQ + s0 + sl) * DIM + d0 + d4];
    sh4 o = {(short)f2bf(v.x), (short)f2bf(v.y), (short)f2bf(v.z), (short)f2bf(v.w)};
    *(sh4*)&L[sl * 72 + d4] = o;
  }
  __syncthreads();
#pragma unroll
  for (int p = 0; p < 4; ++p) {
    const int dl = (t >> 4) + p * 16, s4 = (t & 15) * 4;
    sh4 o = {(short)L[(s4 + 0) * 72 + dl], (short)L[(s4 + 1) * 72 + dl],
             (short)L[(s4 + 2) * 72 + dl], (short)L[(s4 + 3) * 72 + dl]};
    *(sh4*)&T[((size_t)b * DIM + d0 + dl) * SEQ + s0 + s4] = o;
  }
}

// ---------------------------------------------------------------------------
// G1: z[r][d] = sum_e query[r][e] * W[d][e]  (unchanged)
// ---------------------------------------------------------------------------
__global__ __launch_bounds__(256) void g1_z(const float* __restrict__ Q,
                                            const float* __restrict__ W,
                                            unsigned short* __restrict__ zhi,
                                            unsigned short* __restrict__ zlo) {
  __shared__ unsigned short Ah[128 * LDST], Al[128 * LDST];
  __shared__ unsigned short Bh[128 * LDST], Bl[128 * LDST];
  const int tid = threadIdx.x;
  const int m0 = blockIdx.y * 128, n0 = blockIdx.x * 128;
  const int wave = tid >> 6, lane = tid & 63;
  const int wm = (wave >> 1) * 64, wn = (wave & 1) * 64;
  const int rl = tid & 127;

  const float* srow = (tid < 128) ? Q + (size_t)(m0 + rl) * DIM
                                  : W + (size_t)(n0 + rl) * DIM;
  unsigned short* th = (tid < 128) ? Ah : Bh;
  unsigned short* tl = (tid < 128) ? Al : Bl;

  f32x4 acc[4][4];
#pragma unroll
  for (int i = 0; i < 4; ++i)
#pragma unroll
    for (int j = 0; j < 4; ++j) acc[i][j] = (f32x4){0.f, 0.f, 0.f, 0.f};

  for (int kc = 0; kc < DIM; kc += 32) {
    float4 fv[8];
#pragma unroll
    for (int j = 0; j < 8; ++j) fv[j] = *(const float4*)&srow[kc + j * 4];
    __syncthreads();
    short8 hv[4], lv[4];
#pragma unroll
    for (int j = 0; j < 8; ++j) {
      const float x[4] = {fv[j].x, fv[j].y, fv[j].z, fv[j].w};
#pragma unroll
      for (int c = 0; c < 4; ++c) {
        unsigned short h = f2bf(x[c]);
        unsigned short l = f2bf(x[c] - bf2f(h));
        hv[j >> 1][(j & 1) * 4 + c] = (short)h;
        lv[j >> 1][(j & 1) * 4 + c] = (short)l;
      }
    }
#pragma unroll
    for (int j = 0; j < 4; ++j) {
      *(short8*)&th[rl * LDST + j * 8] = hv[j];
      *(short8*)&tl[rl * LDST + j * 8] = lv[j];
    }
    __syncthreads();

    short8 ah[4], al[4], bh[4], bl[4];
#pragma unroll
    for (int f = 0; f < 4; ++f) {
      const int ao = (wm + f * 16 + (lane & 15)) * LDST + (lane >> 4) * 8;
      const int bo = (wn + f * 16 + (lane & 15)) * LDST + (lane >> 4) * 8;
      ah[f] = *(const short8*)&Ah[ao];  al[f] = *(const short8*)&Al[ao];
      bh[f] = *(const short8*)&Bh[bo];  bl[f] = *(const short8*)&Bl[bo];
    }
#pragma unroll
    for (int i = 0; i < 4; ++i)
#pragma unroll
      for (int j = 0; j < 4; ++j) {
        acc[i][j] = __builtin_amdgcn_mfma_f32_16x16x32_bf16(ah[i], bh[j], acc[i][j], 0, 0, 0);
        acc[i][j] = __builtin_amdgcn_mfma_f32_16x16x32_bf16(al[i], bh[j], acc[i][j], 0, 0, 0);
        acc[i][j] = __builtin_amdgcn_mfma_f32_16x16x32_bf16(ah[i], bl[j], acc[i][j], 0, 0, 0);
      }
  }
#pragma unroll
  for (int i = 0; i < 4; ++i)
#pragma unroll
    for (int j = 0; j < 4; ++j)
#pragma unroll
      for (int r = 0; r < 4; ++r) {
        const int row = m0 + wm + i * 16 + (lane >> 4) * 4 + r;
        const int col = n0 + wn + j * 16 + (lane & 15);
        const float v = acc[i][j][r];
        const unsigned short h = f2bf(v);
        zhi[(size_t)row * DIM + col] = h;
        zlo[(size_t)row * DIM + col] = f2bf(v - bf2f(h));
      }
}

// ---------------------------------------------------------------------------
// G2 (pipelined): double-buffered LDS, STAGE(t+1) issued before compute(t),
// raw s_barrier + explicit vmcnt(0) AFTER the MFMA block (prefetch stays in
// flight during compute). One barrier per K-step.
// ---------------------------------------------------------------------------
#define G2GRID (16 * 16 * B_)
__global__ __launch_bounds__(256) void g2_scores(const unsigned short* __restrict__ zhi,
                                                 const unsigned short* __restrict__ zlo,
                                                 const unsigned short* __restrict__ chi,
                                                 const unsigned short* __restrict__ clo,
                                                 float* __restrict__ Sc) {
  __shared__ unsigned short Sh[2][128 * 32], Sl[2][128 * 32];
  __shared__ unsigned short Qh[2][128 * 32], Ql[2][128 * 32];
  const int tid = threadIdx.x, lane = tid & 63, wave = tid >> 6;

  const int lin = blockIdx.x;
  const int swz = (lin & 7) * (G2GRID / 8) + (lin >> 3);
  const int s0 = (swz & 15) * 128;
  const int q0 = ((swz >> 4) & 15) * 128;
  const int b  = swz >> 8;

  const int wm = (wave >> 1) * 64;   // s
  const int wn = (wave & 1) * 64;    // q

  const int r_sub = lane >> 2;
  const int c_sub = (((lane & 3) ^ ((lane >> 3) & 3))) * 8;   // pre-swizzled source col

  // wave-specialized staging source (each wave owns one plane)
  const unsigned short* plane = (wave == 0) ? chi : (wave == 1) ? clo
                              : (wave == 2) ? zhi : zlo;
  const size_t gbase  = (wave < 2) ? ((size_t)b * SEQ + s0) * DIM
                                   : ((size_t)q0 * B_ + b) * DIM;
  const size_t gpitch = (wave < 2) ? (size_t)DIM : (size_t)B_ * DIM;
  const unsigned short* gp = plane + gbase + (size_t)r_sub * gpitch + c_sub;
  unsigned short* lb[2] = {
    (wave == 0) ? Sh[0] : (wave == 1) ? Sl[0] : (wave == 2) ? Qh[0] : Ql[0],
    (wave == 0) ? Sh[1] : (wave == 1) ? Sl[1] : (wave == 2) ? Qh[1] : Ql[1]};

  auto stage = [&](unsigned short* dst, int kc) {
#pragma unroll
    for (int it = 0; it < 8; ++it)
      gl16(gp + (size_t)it * 16 * gpitch + kc, dst + it * 512);
  };

  f32x4 acc[4][4];
#pragma unroll
  for (int i = 0; i < 4; ++i)
#pragma unroll
    for (int j = 0; j < 4; ++j) acc[i][j] = (f32x4){0.f, 0.f, 0.f, 0.f};

  // prologue
  stage(lb[0], 0);
  VMCNT0;
  SBAR; SCHEDB;

  int cur = 0;
  for (int kc = 0; kc < DIM; kc += 32) {
    if (kc + 32 < DIM) stage(lb[cur ^ 1], kc + 32);   // prefetch next tile

    const unsigned short* Shc = Sh[cur];
    const unsigned short* Slc = Sl[cur];
    const unsigned short* Qhc = Qh[cur];
    const unsigned short* Qlc = Ql[cur];
    short8 sh_[4], sl_[4], qh_[4], ql_[4];
#pragma unroll
    for (int f = 0; f < 4; ++f) {
      const int ra = wm + f * 16 + (lane & 15);
      const int rb = wn + f * 16 + (lane & 15);
      const int so = ra * 32 + (((lane >> 4) ^ ((ra >> 1) & 3))) * 8;
      const int qo = rb * 32 + (((lane >> 4) ^ ((rb >> 1) & 3))) * 8;
      sh_[f] = *(const short8*)&Shc[so];  sl_[f] = *(const short8*)&Slc[so];
      qh_[f] = *(const short8*)&Qhc[qo];  ql_[f] = *(const short8*)&Qlc[qo];
    }
#pragma unroll
    for (int i = 0; i < 4; ++i)
#pragma unroll
      for (int j = 0; j < 4; ++j) {
        acc[i][j] = __builtin_amdgcn_mfma_f32_16x16x32_bf16(sh_[i], qh_[j], acc[i][j], 0, 0, 0);
        acc[i][j] = __builtin_amdgcn_mfma_f32_16x16x32_bf16(sl_[i], qh_[j], acc[i][j], 0, 0, 0);
        acc[i][j] = __builtin_amdgcn_mfma_f32_16x16x32_bf16(sh_[i], ql_[j], acc[i][j], 0, 0, 0);
      }
    VMCNT0;                    // prefetch (issued pre-compute) now landed
    SCHEDB; SBAR; SCHEDB;      // single barrier per K-step
    cur ^= 1;
  }

#pragma unroll
  for (int i = 0; i < 4; ++i)
#pragma unroll
    for (int j = 0; j < 4; ++j) {
      const int s = s0 + wm + i * 16 + (lane >> 4) * 4;
      const int q = q0 + wn + j * 16 + (lane & 15);
      f32x4 v = {acc[i][j][0], acc[i][j][1], acc[i][j][2], acc[i][j][3]};
      __builtin_nontemporal_store(v, (f32x4*)&Sc[((size_t)q * B_ + b) * SEQ + s]);
    }
}

// ---------------------------------------------------------------------------
// softmax: in-place, float4-vectorized
// ---------------------------------------------------------------------------
__global__ __launch_bounds__(256) void kernel_softmax(float* __restrict__ attn,
                                                      const int* __restrict__ mask) {
  const int row = blockIdx.x;       // q*B_ + b
  const int b = row & (B_ - 1);
  float* p = attn + (size_t)row * SEQ;
  const int* m = mask + (size_t)b * SEQ;
  const int t = threadIdx.x;

  float4 va = *(const float4*)&p[t * 8];
  float4 vb = *(const float4*)&p[t * 8 + 4];
  int4 ma = *(const int4*)&m[t * 8];
  int4 mb = *(const int4*)&m[t * 8 + 4];
  float v[8] = {ma.x ? -1e30f : va.x, ma.y ? -1e30f : va.y,
                ma.z ? -1e30f : va.z, ma.w ? -1e30f : va.w,
                mb.x ? -1e30f : vb.x, mb.y ? -1e30f : vb.y,
                mb.z ? -1e30f : vb.z, mb.w ? -1e30f : vb.w};
  float mx = -INFINITY;
#pragma unroll
  for (int i = 0; i < 8; ++i) mx = fmaxf(mx, v[i]);
#pragma unroll
  for (int off = 32; off > 0; off >>= 1) mx = fmaxf(mx, __shfl_xor(mx, off));
  __shared__ float redmax[4];
  __shared__ float redsum[4];
  if ((t & 63) == 0) redmax[t >> 6] = mx;
  __syncthreads();
  mx = fmaxf(fmaxf(redmax[0], redmax[1]), fmaxf(redmax[2], redmax[3]));

  float sum = 0.f;
#pragma unroll
  for (int i = 0; i < 8; ++i) {
    v[i] = __expf(v[i] - mx);
    sum += v[i];
  }
#pragma unroll
  for (int off = 32; off > 0; off >>= 1) sum += __shfl_xor(sum, off);
  if ((t & 63) == 0) redsum[t >> 6] = sum;
  __syncthreads();
  sum = (redsum[0] + redsum[1]) + (redsum[2] + redsum[3]);

  const bool allmasked = (mx < -1e29f);
  const float inv = allmasked ? 0.f : 1.f / sum;
  float4 oa = {v[0] * inv, v[1] * inv, v[2] * inv, v[3] * inv};
  float4 ob = {v[4] * inv, v[5] * inv, v[6] * inv, v[7] * inv};
  *(float4*)&p[t * 8] = oa;
  *(float4*)&p[t * 8 + 4] = ob;
}

// ---------------------------------------------------------------------------
// G3 (pipelined): A = ctxT d-rows (gl16), B = attn f32 -> bf16 reg-staged
// with issue-early / write-late split; double-buffered LDS, raw barriers.
// ---------------------------------------------------------------------------
__global__ __launch_bounds__(256) void g3_comp(const float* __restrict__ attn,
                                               const unsigned short* __restrict__ ctxT,
                                               float* __restrict__ Out) {
  __shared__ unsigned short Ad[2][128 * 32];
  __shared__ unsigned short Bq[2][128 * 32];
  const int tid = threadIdx.x, lane = tid & 63, wave = tid >> 6;
  const int b = blockIdx.z;
  const int d0 = blockIdx.x * 128, q0 = blockIdx.y * 128;
  const int wm = (wave >> 1) * 64;   // d
  const int wn = (wave & 1) * 64;    // q

  const int r_sub = lane >> 2;
  const int c_sub = (((lane & 3) ^ ((lane >> 3) & 3))) * 8;

  // A staging: wave stages rows [wave*32, wave*32+32)
  const unsigned short* agp =
      ctxT + ((size_t)b * DIM + d0 + wave * 32 + r_sub) * SEQ + c_sub;
  auto stageA = [&](unsigned short* dst, int kc) {
#pragma unroll
    for (int i = 0; i < 2; ++i)
      gl16(agp + (size_t)i * 16 * SEQ + kc, dst + (wave * 32 + i * 16) * 32);
  };

  // B reg-staging geometry
  const int qrow = tid >> 1, shalf = (tid & 1) * 16;
  const float* arow = attn + ((size_t)(q0 + qrow) * B_ + b) * SEQ;
  const int qsw = (qrow >> 1) & 3;
  const int blk_base = (tid & 1) * 2;
  const int bo0 = qrow * 32 + ((blk_base + 0) ^ qsw) * 8;
  const int bo1 = qrow * 32 + ((blk_base + 1) ^ qsw) * 8;

  f32x4 acc[4][4];
#pragma unroll
  for (int i = 0; i < 4; ++i)
#pragma unroll
    for (int j = 0; j < 4; ++j) acc[i][j] = (f32x4){0.f, 0.f, 0.f, 0.f};

  // prologue: stage tile 0
  float4 pv[4];
#pragma unroll
  for (int j = 0; j < 4; ++j) pv[j] = *(const float4*)&arow[shalf + j * 4];
  stageA(Ad[0], 0);
  VMCNT0;
  {
    short8 b0, b1;
#pragma unroll
    for (int j = 0; j < 4; ++j) {
      const float x[4] = {pv[j].x, pv[j].y, pv[j].z, pv[j].w};
#pragma unroll
      for (int c = 0; c < 4; ++c) {
        const int e = j * 4 + c;
        if (e < 8) b0[e] = (short)f2bf(x[c]);
        else       b1[e - 8] = (short)f2bf(x[c]);
      }
    }
    *(short8*)&Bq[0][bo0] = b0;
    *(short8*)&Bq[0][bo1] = b1;
  }
  LGKMCNT0;
  SBAR; SCHEDB;

  int cur = 0;
  for (int kc = 0; kc < SEQ; kc += 32) {
    const bool more = (kc + 32 < SEQ);
    float4 nv[4];
    if (more) {
#pragma unroll
      for (int j = 0; j < 4; ++j) nv[j] = *(const float4*)&arow[kc + 32 + shalf + j * 4];
      stageA(Ad[cur ^ 1], kc + 32);
    }

    const unsigned short* Adc = Ad[cur];
    const unsigned short* Bqc = Bq[cur];
    short8 af[4], bf_[4];
#pragma unroll
    for (int f = 0; f < 4; ++f) {
      const int ra = wm + f * 16 + (lane & 15);
      const int rb = wn + f * 16 + (lane & 15);
      af[f]  = *(const short8*)&Adc[ra * 32 + (((lane >> 4) ^ ((ra >> 1) & 3))) * 8];
      bf_[f] = *(const short8*)&Bqc[rb * 32 + (((lane >> 4) ^ ((rb >> 1) & 3))) * 8];
    }
#pragma unroll
    for (int i = 0; i < 4; ++i)
#pragma unroll
      for (int j = 0; j < 4; ++j)
        acc[i][j] = __builtin_amdgcn_mfma_f32_16x16x32_bf16(af[i], bf_[j], acc[i][j], 0, 0, 0);

    VMCNT0;                        // nv loads + gl16 landed
    if (more) {
      short8 b0, b1;
#pragma unroll
      for (int j = 0; j < 4; ++j) {
        const float x[4] = {nv[j].x, nv[j].y, nv[j].z, nv[j].w};
#pragma unroll
        for (int c = 0; c < 4; ++c) {
          const int e = j * 4 + c;
          if (e < 8) b0[e] = (short)f2bf(x[c]);
          else       b1[e - 8] = (short)f2bf(x[c]);
        }
      }
      unsigned short* Bqn = Bq[cur ^ 1];
      *(short8*)&Bqn[bo0] = b0;
      *(short8*)&Bqn[bo1] = b1;
    }
    LGKMCNT0;
    SCHEDB; SBAR; SCHEDB;
    cur ^= 1;
  }

#pragma unroll
  for (int i = 0; i < 4; ++i)
#pragma unroll
    for (int j = 0; j < 4; ++j) {
      const int d = d0 + wm + i * 16 + (lane >> 4) * 4;
      const int q = q0 + wn + j * 16 + (lane & 15);
      f32x4 v = {acc[i][j][0], acc[i][j][1], acc[i][j][2], acc[i][j][3]};
      __builtin_nontemporal_store(v, (f32x4*)&Out[((size_t)q * B_ + b) * DIM + d]);
    }
}

extern "C" void kernel_launch(void* const* d_in, const int* in_sizes, int n_in,
                              void* d_out, int out_size, void* d_ws, size_t ws_size,
                              hipStream_t stream) {
  const float* context = (const float*)d_in[0];   // [B, SEQ, DIM]
  const float* query   = (const float*)d_in[1];   // [SEQ, B, DIM]
  const float* W       = (const float*)d_in[2];   // [DIM, DIM]
  const int*   mask    = (const int*)d_in[3];     // [B, SEQ] bool->int32

  float* attn = (float*)d_out;                     // [SEQ, B, SEQ]  (256 MiB)
  float* comp = attn + (size_t)SEQ * B_ * SEQ;     // [SEQ, B, DIM]  (128 MiB)

  unsigned short* chi = (unsigned short*)comp;                     // 64 MiB
  unsigned short* clo = chi + (size_t)B_ * SEQ * DIM;              // 64 MiB

  unsigned short* zhi  = (unsigned short*)d_ws;                    // 64 MiB
  unsigned short* zlo  = zhi + (size_t)SEQ * B_ * DIM;             // 64 MiB
  unsigned short* ctxT = (unsigned short*)d_ws;                    // reuses z after G2

  // 0) ctx -> bf16 hi/lo planes (comp region; dead until G3)
  cvt_ctx<<<dim3(4096), 256, 0, stream>>>(context, chi, clo);
  // 1) z = W @ query (flat rows), bf16x2
  g1_z<<<dim3(DIM / 128, (SEQ * B_) / 128), 256, 0, stream>>>(query, W, zhi, zlo);
  // 2) scores -> attn region (pipelined dbuf)
  g2_scores<<<dim3(G2GRID), 256, 0, stream>>>(zhi, zlo, chi, clo, attn);
  // 2b) ctxT bf16 [b][d][s] into d_ws (z dead now)
  t_ctx<<<dim3(DIM / 64, SEQ / 64, B_), 256, 0, stream>>>(context, ctxT);
  // 3) masked softmax in place
  kernel_softmax<<<dim3(SEQ * B_), 256, 0, stream>>>(attn, mask);
  // 4) comp = attn @ ctx via ctxT (pipelined dbuf)
  g3_comp<<<dim3(DIM / 128, SEQ / 128, B_), 256, 0, stream>>>(attn, ctxT, comp);
}